// Round 18
// baseline (263.398 us; speedup 1.0000x reference)
//
#include <hip/hip_runtime.h>
#include <math.h>

constexpr int B = 2, C = 16, H = 128, W = 128;
constexpr int HW = H * W;

// xpad: [B,16,146,148]; orig (h,w) -> (h+9, w+9); pads zeroed by conv1
constexpr int XR = 146, XS = 148, XCH = XR * XS;
constexpr size_t XPAD_ELEMS = (size_t)B * C * XCH;

// ypad: [B,16,130,136]; orig (h,w) -> (h+1, w+4); pads zeroed by kpn19
constexpr int YR = 130, YS = 136, YCH = YR * YS;

__device__ __forceinline__ float4 ld4(const float* p) { return *(const float4*)p; }

// ===========================================================================
// kpn19: wide-LDS restructure. Thread = 4 consecutive px (px0 = pq*4) x 1 ch
// x 1 kh-quarter. Block = 4 q x (16 pq x 16 ch) = 1024 thr; grid = wb2 x
// h128 x b2 = 512 (2 blocks/CU).
// Per row per thread: x window = 6 ds_read_b128 (aligned, 8 words/bank
// uniform), kern = 19 ds_read_b128 (16 distinct float4/wave + 4-way
// broadcast, ~conflict-free), 76 FMA with static register-select (XC).
// Staging per row per wave: EXACTLY 4 global_load_lds (x: 64+20 lanes,
// kern: 64+12 lanes; the predicated instrs have active lanes in EVERY wave
// -> uniform vmcnt ticks). Counted vmcnt(4) + raw s_barrier; no mid-loop
// drain. LDS pool = 4 q x 2 buf x (1344 x-floats + 1216 k-floats) = 80 KB
// exactly -> 2 blocks/CU. Reduction aliases the pool after drain+barrier.
// ===========================================================================
constexpr int BUFS = 2560, KOFF = 1344, QSTR = 2 * BUFS;

#define XC(A, I)                                                             \
  (((I) & 3) == 0 ? A[(I) >> 2].x : ((I) & 3) == 1 ? A[(I) >> 2].y           \
   : ((I) & 3) == 2 ? A[(I) >> 2].z : A[(I) >> 2].w)

__global__ __launch_bounds__(1024) void kpn19(
    const float* __restrict__ xpad,  // [B,16,146,148]
    const float* __restrict__ kern,  // [B,361,128,128]
    float* __restrict__ ypad)        // [B,16,130,136]
{
    __shared__ __align__(16) float pool[4 * QSTR];   // 81,920 B exactly

    int tid  = threadIdx.x;
    int lane = tid & 63;
    int w    = (tid >> 6) & 3;       // wave within q-group (uniform)
    int q    = tid >> 8;             // kh-quarter (uniform)
    int idx  = tid & 255;
    int pq   = idx & 15;
    int ch   = idx >> 4;
    int blk  = blockIdx.x;           // 512 = wb2 x h128 x b2
    int wb   = blk & 1;
    int h    = (blk >> 1) & 127;
    int b    = blk >> 8;
    int w0   = wb * 64;

    // ---- ypad pad zeroing (replaces memset) ----
    if (tid < 64) {
        int pl = tid >> 2, i = tid & 3;
        int col = wb ? 132 + i : i;
        ypad[((size_t)(b * C + pl) * YR + (h + 1)) * YS + col] = 0.f;
    }
    if (h == 0 || h == 127) {
        int r = (h == 0) ? 0 : 129;
        for (int f = tid; f < 1088; f += 1024) {
            int pl = f / 68, col = wb * 68 + f % 68;
            ypad[((size_t)(b * C + pl) * YR + r) * YS + col] = 0.f;
        }
    }
    // stores count in vmcnt: flush before the counted pipeline
    asm volatile("s_waitcnt vmcnt(0)" ::: "memory");
    __builtin_amdgcn_sched_barrier(0);

    // ---- staging sources (per-lane, khs-invariant parts precomputed) ----
    int m1 = w * 84 + lane;                       // x chunk, always < 336
    int m2 = w * 84 + 64 + lane; if (m2 > 335) m2 = 335;   // lanes<20 real
    int xc1 = m1 / 21, xo1 = m1 % 21;
    int xc2 = m2 / 21, xo2 = m2 % 21;
    const float* xs1 = xpad + (size_t)(b * C + xc1) * XCH + (size_t)h * XS + w0 + xo1 * 4;
    const float* xs2 = xpad + (size_t)(b * C + xc2) * XCH + (size_t)h * XS + w0 + xo2 * 4;
    int n1 = w * 76 + lane;                       // kern chunk, always < 304
    int n2 = w * 76 + 64 + lane; if (n2 > 303) n2 = 303;   // lanes<12 real
    const float* ks1 = kern + (size_t)(b * 361 + (n1 >> 4)) * HW + (size_t)h * W + w0 + (n1 & 15) * 4;
    const float* ks2 = kern + (size_t)(b * 361 + (n2 >> 4)) * HW + (size_t)h * W + w0 + (n2 & 15) * 4;

    int kh0 = q * 5;
    int nkh = (q == 3) ? 4 : 5;

    auto STAGE = [&](int bufsel, int khs) {
        int khx = (khs > 18) ? 18 : khs;          // dummy rows clamped (valid)
        float* xd = pool + q * QSTR + bufsel * BUFS + w * 336;
        __builtin_amdgcn_global_load_lds((const void*)(xs1 + (size_t)khx * XS),
                                         (void*)xd, 16, 0, 0);
        if (lane < 20)
            __builtin_amdgcn_global_load_lds((const void*)(xs2 + (size_t)khx * XS),
                                             (void*)(xd + 256), 16, 0, 0);
        float* kd = pool + q * QSTR + bufsel * BUFS + KOFF + w * 304;
        __builtin_amdgcn_global_load_lds((const void*)(ks1 + (size_t)khx * 19 * HW),
                                         (void*)kd, 16, 0, 0);
        if (lane < 12)
            __builtin_amdgcn_global_load_lds((const void*)(ks2 + (size_t)khx * 19 * HW),
                                             (void*)(kd + 256), 16, 0, 0);
    };

    float4 acc = make_float4(0.f, 0.f, 0.f, 0.f);

#define FMABODY(cur)                                                         \
  {                                                                          \
    const float* xb_ = pool + q * QSTR + (cur) * BUFS + ch * 84 + pq * 4;    \
    float4 xw[6];                                                            \
    _Pragma("unroll")                                                        \
    for (int t = 0; t < 6; ++t) xw[t] = ld4(xb_ + 4 * t);                    \
    const float* kb_ = pool + q * QSTR + (cur) * BUFS + KOFF + pq * 4;       \
    _Pragma("unroll")                                                        \
    for (int kw = 0; kw < 19; ++kw) {                                        \
      float4 kq = ld4(kb_ + kw * 64);                                        \
      acc.x = fmaf(XC(xw, kw + 0), kq.x, acc.x);                             \
      acc.y = fmaf(XC(xw, kw + 1), kq.y, acc.y);                             \
      acc.z = fmaf(XC(xw, kw + 2), kq.z, acc.z);                             \
      acc.w = fmaf(XC(xw, kw + 3), kq.w, acc.w);                             \
    }                                                                        \
  }

    // Prologue: stage row kh0 into buf0 (4 ticks).
    STAGE(0, kh0);

    #pragma unroll
    for (int r = 0; r < 4; ++r) {
        STAGE((r + 1) & 1, kh0 + r + 1);          // 4 ticks (uniform)
        asm volatile("s_waitcnt vmcnt(4)" ::: "memory");
        __builtin_amdgcn_sched_barrier(0);
        __builtin_amdgcn_s_barrier();
        __builtin_amdgcn_sched_barrier(0);
        FMABODY(r & 1);                            // r<4 <= nkh always
        __builtin_amdgcn_sched_barrier(0);
        __builtin_amdgcn_s_barrier();
    }
    // r = 4: nothing staged this iter -> drain all, then compute (q<3 only)
    asm volatile("s_waitcnt vmcnt(0)" ::: "memory");
    __builtin_amdgcn_sched_barrier(0);
    __builtin_amdgcn_s_barrier();
    __builtin_amdgcn_sched_barrier(0);
    if (4 < nkh) FMABODY(0);
#undef FMABODY

    // ---- reduce quarters: alias pool (all staging landed, all FMAs done) ----
    __syncthreads();
    if (q > 0) *(float4*)(pool + (q - 1) * 1024 + idx * 4) = acc;
    __syncthreads();
    if (q == 0) {
        #pragma unroll
        for (int j = 0; j < 3; ++j) {
            float4 rv = ld4(pool + j * 1024 + idx * 4);
            acc.x += rv.x; acc.y += rv.y; acc.z += rv.z; acc.w += rv.w;
        }
        float* yp = ypad + ((size_t)(b * C + ch) * YR + (h + 1)) * YS + (w0 + pq * 4 + 4);
        *(float4*)yp = acc;
    }
}

// ===========================================================================
// conv1 (FROZEN r17): LDS row-staged, #pragma unroll 1 on ic (spill-free).
// ===========================================================================
__global__ __launch_bounds__(256) void conv1_gelu(
    const float* __restrict__ in, const float* __restrict__ w1,
    const float* __restrict__ b1, float* __restrict__ xpad)
{
    __shared__ float ws[2304];
    __shared__ float bs[16];
    __shared__ __align__(16) float xs[16][3][128];   // 24 KB

    int tid = threadIdx.x;
    for (int i = tid; i < 2304; i += 256) ws[i] = w1[i];
    if (tid < 16) bs[tid] = b1[tid];

    int px  = tid & 127;
    int ocg = tid >> 7;
    int blk = blockIdx.x;                // 512 = half2 x h128 x b2
    int half = blk & 1;
    int h   = (blk >> 1) & 127;
    int b   = blk >> 8;
    int oc0 = half * 8 + ocg * 4;

    if (tid < 160) {
        int j = tid / 20, i = tid % 20;
        int col = (i < 9) ? i : 128 + i;
        xpad[((size_t)(b * C + half * 8 + j) * XR + (h + 9)) * XS + col] = 0.f;
    }
    if (h == 0 || h == 127) {
        int r0 = (h == 0) ? 0 : 137;
        for (int f = tid; f < 8 * 9 * XS; f += 256) {
            int j = f / (9 * XS), rem = f % (9 * XS);
            int r = r0 + rem / XS, col = rem % XS;
            xpad[((size_t)(b * C + half * 8 + j) * XR + r) * XS + col] = 0.f;
        }
    }

    const float4 z4 = make_float4(0.f, 0.f, 0.f, 0.f);
    #pragma unroll
    for (int j = 0; j < 6; ++j) {
        int m = tid + j * 256;
        int ic = m / 96, rem = m - ic * 96, r = rem >> 5, qq = rem & 31;
        int row = h + r - 1;
        float4 v = ((unsigned)row < 128u)
                 ? ld4(in + ((size_t)(b * C + ic) * H + row) * W + qq * 4) : z4;
        *(float4*)&xs[ic][r][qq * 4] = v;
    }
    __syncthreads();

    bool wm = (px > 0), wp = (px < 127);
    float a0 = 0.f, a1 = 0.f, a2 = 0.f, a3 = 0.f;

    #pragma unroll 1
    for (int ic = 0; ic < 16; ++ic) {
        float t[9];
        #pragma unroll
        for (int r = 0; r < 3; ++r) {
            t[r * 3 + 0] = wm ? xs[ic][r][px - 1] : 0.f;
            t[r * 3 + 1] = xs[ic][r][px];
            t[r * 3 + 2] = wp ? xs[ic][r][px + 1] : 0.f;
        }
        #pragma unroll
        for (int j = 0; j < 4; ++j) {
            const float* wp9 = ws + (oc0 + j) * 144 + ic * 9;
            float s = fmaf(wp9[0], t[0], fmaf(wp9[1], t[1], fmaf(wp9[2], t[2],
                      fmaf(wp9[3], t[3], fmaf(wp9[4], t[4], fmaf(wp9[5], t[5],
                      fmaf(wp9[6], t[6], fmaf(wp9[7], t[7], wp9[8] * t[8]))))))));
            if (j == 0) a0 += s; else if (j == 1) a1 += s;
            else if (j == 2) a2 += s; else a3 += s;
        }
    }

    float* xp = xpad + ((size_t)(b * C + oc0) * XR + (h + 9)) * XS + (px + 9);
    float v;
    v = a0 + bs[oc0 + 0]; xp[0]       = 0.5f * v * (1.0f + erff(v * 0.70710678f));
    v = a1 + bs[oc0 + 1]; xp[XCH]     = 0.5f * v * (1.0f + erff(v * 0.70710678f));
    v = a2 + bs[oc0 + 2]; xp[2 * XCH] = 0.5f * v * (1.0f + erff(v * 0.70710678f));
    v = a3 + bs[oc0 + 3]; xp[3 * XCH] = 0.5f * v * (1.0f + erff(v * 0.70710678f));
}

// ===========================================================================
// conv2 (FROZEN r17): LDS row-staged, #pragma unroll 1 on ic.
// ===========================================================================
__global__ __launch_bounds__(256) void conv2_sig(
    const float* __restrict__ ypad, const float* __restrict__ w2,
    const float* __restrict__ b2, float* __restrict__ out)
{
    __shared__ float ws[2304];
    __shared__ float bs[16];
    __shared__ __align__(16) float ys[16][3][136];   // 26.1 KB

    int tid = threadIdx.x;
    for (int i = tid; i < 2304; i += 256) ws[i] = w2[i];
    if (tid < 16) bs[tid] = b2[tid];

    int px  = tid & 127;
    int ocg = tid >> 7;
    int blk = blockIdx.x;                // 512 = half2 x h128 x b2
    int half = blk & 1;
    int h   = (blk >> 1) & 127;
    int b   = blk >> 8;
    int oc0 = half * 8 + ocg * 4;

    #pragma unroll
    for (int j = 0; j < 7; ++j) {
        int m = tid + j * 256;
        if (m < 1632) {
            int ic = m / 102, rem = m - ic * 102, r = rem / 34, qq = rem % 34;
            float4 v = ld4(ypad + ((size_t)(b * C + ic) * YR + (h + r)) * YS + qq * 4);
            *(float4*)&ys[ic][r][qq * 4] = v;
        }
    }
    __syncthreads();

    float a0 = 0.f, a1 = 0.f, a2 = 0.f, a3 = 0.f;

    #pragma unroll 1
    for (int ic = 0; ic < 16; ++ic) {
        float t[9];
        #pragma unroll
        for (int r = 0; r < 3; ++r) {
            t[r * 3 + 0] = ys[ic][r][px + 3];
            t[r * 3 + 1] = ys[ic][r][px + 4];
            t[r * 3 + 2] = ys[ic][r][px + 5];
        }
        #pragma unroll
        for (int j = 0; j < 4; ++j) {
            const float* wp9 = ws + (oc0 + j) * 144 + ic * 9;
            float s = fmaf(wp9[0], t[0], fmaf(wp9[1], t[1], fmaf(wp9[2], t[2],
                      fmaf(wp9[3], t[3], fmaf(wp9[4], t[4], fmaf(wp9[5], t[5],
                      fmaf(wp9[6], t[6], fmaf(wp9[7], t[7], wp9[8] * t[8]))))))));
            if (j == 0) a0 += s; else if (j == 1) a1 += s;
            else if (j == 2) a2 += s; else a3 += s;
        }
    }

    float* op = out + ((size_t)(b * C + oc0) * H + h) * W + px;
    float v;
    v = a0 + bs[oc0 + 0]; op[0]      = 1.0f / (1.0f + expf(-v));
    v = a1 + bs[oc0 + 1]; op[HW]     = 1.0f / (1.0f + expf(-v));
    v = a2 + bs[oc0 + 2]; op[2 * HW] = 1.0f / (1.0f + expf(-v));
    v = a3 + bs[oc0 + 3]; op[3 * HW] = 1.0f / (1.0f + expf(-v));
}

// ---------------------------------------------------------------------------
extern "C" void kernel_launch(void* const* d_in, const int* in_sizes, int n_in,
                              void* d_out, int out_size, void* d_ws, size_t ws_size,
                              hipStream_t stream)
{
    const float* input  = (const float*)d_in[0];
    const float* kernel = (const float*)d_in[1];
    const float* w1     = (const float*)d_in[2];
    const float* b1     = (const float*)d_in[3];
    const float* w2     = (const float*)d_in[4];
    const float* b2     = (const float*)d_in[5];
    float* out = (float*)d_out;

    float* xpad = (float*)d_ws;
    float* ypad = xpad + XPAD_ELEMS;

    conv1_gelu<<<512, 256, 0, stream>>>(input, w1, b1, xpad);
    kpn19<<<512, 1024, 0, stream>>>(xpad, kernel, ypad);
    conv2_sig<<<512, 256, 0, stream>>>(ypad, w2, b2, out);
}

// Round 19
// 62.792 us; speedup vs baseline: 4.1948x; 4.1948x over previous
//
#include <hip/hip_runtime.h>
#include <math.h>

constexpr int B = 2, C = 16, H = 128, W = 128;
constexpr int HW = H * W;

// xpad: [B,16,146,148]; orig (h,w) -> (h+9, w+9); pads zeroed by conv1
constexpr int XR = 146, XS = 148, XCH = XR * XS;
constexpr size_t XPAD_ELEMS = (size_t)B * C * XCH;

// ypad: [B,16,130,136]; orig (h,w) -> (h+1, w+4); pads zeroed by kpn19
constexpr int YR = 130, YS = 136, YCH = YR * YS;

__device__ __forceinline__ float4 ld4(const float* p) { return *(const float4*)p; }

// ===========================================================================
// kpn19: wide-LDS layout (r18) with the spill fixed and sync simplified.
// Thread = 4 px (px0 = pq*4) x 1 ch x 1 kh-quarter. Block = 4q x 16pq x 16ch
// = 1024 thr; grid = wb2 x h128 x b2 = 512 (2 blocks/CU, LDS 80KB).
// KEY FIX vs r18: __launch_bounds__(1024, 4) -> 128-VGPR budget (r18's
// default targeted 8 waves/EU -> 64 VGPR -> 461 MB scratch-spill storm).
// Sync: r16-proven vmcnt(0)+__syncthreads once per row; STAGE(next) issued
// before the FMAs so staging overlaps compute.
// Per row per thread: 6 ds_read_b128 (x window, uniform 8 words/bank since
// 84 mod 32 = 20 with 4 ch-rotations) + 19 ds_read_b128 (kern, 16 distinct
// chunks + 4-way broadcast) + 76 FMA.  25 wide LDS reads vs r16's 76 narrow.
// ===========================================================================
constexpr int BUFS = 2560, KOFF = 1344, QSTR = 2 * BUFS;   // floats

#define XC(A, I)                                                             \
  (((I) & 3) == 0 ? A[(I) >> 2].x : ((I) & 3) == 1 ? A[(I) >> 2].y           \
   : ((I) & 3) == 2 ? A[(I) >> 2].z : A[(I) >> 2].w)

__global__ __launch_bounds__(1024, 4) void kpn19(
    const float* __restrict__ xpad,  // [B,16,146,148]
    const float* __restrict__ kern,  // [B,361,128,128]
    float* __restrict__ ypad)        // [B,16,130,136]
{
    __shared__ __align__(16) float pool[4 * QSTR];   // 81,920 B exactly

    int tid  = threadIdx.x;
    int lane = tid & 63;
    int w    = (tid >> 6) & 3;       // wave within q-group (uniform)
    int q    = tid >> 8;             // kh-quarter (uniform)
    int idx  = tid & 255;
    int pq   = idx & 15;
    int ch   = idx >> 4;
    int blk  = blockIdx.x;           // 512 = wb2 x h128 x b2
    int wb   = blk & 1;
    int h    = (blk >> 1) & 127;
    int b    = blk >> 8;
    int w0   = wb * 64;

    // ---- ypad pad zeroing (replaces memset) ----
    if (tid < 64) {
        int pl = tid >> 2, i = tid & 3;
        int col = wb ? 132 + i : i;
        ypad[((size_t)(b * C + pl) * YR + (h + 1)) * YS + col] = 0.f;
    }
    if (h == 0 || h == 127) {
        int r = (h == 0) ? 0 : 129;
        for (int f = tid; f < 1088; f += 1024) {
            int pl = f / 68, col = wb * 68 + f % 68;
            ypad[((size_t)(b * C + pl) * YR + r) * YS + col] = 0.f;
        }
    }

    // ---- staging sources ----
    int m1 = w * 84 + lane;                                  // x chunk < 336
    int m2 = w * 84 + 64 + lane; if (m2 > 335) m2 = 335;     // lanes<20 real
    const float* xs1 = xpad + (size_t)(b * C + m1 / 21) * XCH
                       + (size_t)h * XS + w0 + (m1 % 21) * 4;
    const float* xs2 = xpad + (size_t)(b * C + m2 / 21) * XCH
                       + (size_t)h * XS + w0 + (m2 % 21) * 4;
    int n1 = w * 76 + lane;                                  // kern chunk < 304
    int n2 = w * 76 + 64 + lane; if (n2 > 303) n2 = 303;     // lanes<12 real
    const float* ks1 = kern + (size_t)(b * 361 + (n1 >> 4)) * HW
                       + (size_t)h * W + w0 + (n1 & 15) * 4;
    const float* ks2 = kern + (size_t)(b * 361 + (n2 >> 4)) * HW
                       + (size_t)h * W + w0 + (n2 & 15) * 4;

    int kh0 = q * 5;
    int nkh = (q == 3) ? 4 : 5;

    auto STAGE = [&](int buf, int row) {     // row = kh offset from h
        float* xd = pool + q * QSTR + buf * BUFS + w * 336;  // wave-uniform
        __builtin_amdgcn_global_load_lds(
            (const void*)(xs1 + (size_t)row * XS), (void*)xd, 16, 0, 0);
        if (lane < 20)
            __builtin_amdgcn_global_load_lds(
                (const void*)(xs2 + (size_t)row * XS), (void*)(xd + 256), 16, 0, 0);
        float* kd = pool + q * QSTR + buf * BUFS + KOFF + w * 304;
        __builtin_amdgcn_global_load_lds(
            (const void*)(ks1 + (size_t)row * 19 * HW), (void*)kd, 16, 0, 0);
        if (lane < 12)
            __builtin_amdgcn_global_load_lds(
                (const void*)(ks2 + (size_t)row * 19 * HW), (void*)(kd + 256), 16, 0, 0);
    };

    float4 acc = make_float4(0.f, 0.f, 0.f, 0.f);

    // Prologue: stage row kh0 into buf 0; drain (also covers pad-zero stores).
    STAGE(0, kh0);
    asm volatile("s_waitcnt vmcnt(0)" ::: "memory");
    __syncthreads();

    for (int r = 0; r < 5; ++r) {            // 5 sync rounds for ALL waves
        int cur = r & 1;
        if (r + 1 < nkh) STAGE(cur ^ 1, kh0 + r + 1);   // overlaps compute
        if (r < nkh) {
            const float* xb_ = pool + q * QSTR + cur * BUFS + ch * 84 + pq * 4;
            float4 xw[6];
            #pragma unroll
            for (int t = 0; t < 6; ++t) xw[t] = ld4(xb_ + 4 * t);
            const float* kb_ = pool + q * QSTR + cur * BUFS + KOFF + pq * 4;
            #pragma unroll
            for (int kw = 0; kw < 19; ++kw) {
                float4 kq = ld4(kb_ + kw * 64);
                acc.x = fmaf(XC(xw, kw + 0), kq.x, acc.x);
                acc.y = fmaf(XC(xw, kw + 1), kq.y, acc.y);
                acc.z = fmaf(XC(xw, kw + 2), kq.z, acc.z);
                acc.w = fmaf(XC(xw, kw + 3), kq.w, acc.w);
            }
        }
        asm volatile("s_waitcnt vmcnt(0)" ::: "memory");
        __syncthreads();
    }

    // ---- reduce quarters: alias pool (all staging landed, all reads done) ----
    if (q > 0) *(float4*)(pool + (q - 1) * 1024 + idx * 4) = acc;
    __syncthreads();
    if (q == 0) {
        #pragma unroll
        for (int j = 0; j < 3; ++j) {
            float4 rv = ld4(pool + j * 1024 + idx * 4);
            acc.x += rv.x; acc.y += rv.y; acc.z += rv.z; acc.w += rv.w;
        }
        float* yp = ypad + ((size_t)(b * C + ch) * YR + (h + 1)) * YS + (w0 + pq * 4 + 4);
        *(float4*)yp = acc;
    }
}

// ===========================================================================
// conv1 (FROZEN r17): LDS row-staged, #pragma unroll 1 on ic (spill-free).
// ===========================================================================
__global__ __launch_bounds__(256) void conv1_gelu(
    const float* __restrict__ in, const float* __restrict__ w1,
    const float* __restrict__ b1, float* __restrict__ xpad)
{
    __shared__ float ws[2304];
    __shared__ float bs[16];
    __shared__ __align__(16) float xs[16][3][128];   // 24 KB

    int tid = threadIdx.x;
    for (int i = tid; i < 2304; i += 256) ws[i] = w1[i];
    if (tid < 16) bs[tid] = b1[tid];

    int px  = tid & 127;
    int ocg = tid >> 7;
    int blk = blockIdx.x;                // 512 = half2 x h128 x b2
    int half = blk & 1;
    int h   = (blk >> 1) & 127;
    int b   = blk >> 8;
    int oc0 = half * 8 + ocg * 4;

    if (tid < 160) {
        int j = tid / 20, i = tid % 20;
        int col = (i < 9) ? i : 128 + i;
        xpad[((size_t)(b * C + half * 8 + j) * XR + (h + 9)) * XS + col] = 0.f;
    }
    if (h == 0 || h == 127) {
        int r0 = (h == 0) ? 0 : 137;
        for (int f = tid; f < 8 * 9 * XS; f += 256) {
            int j = f / (9 * XS), rem = f % (9 * XS);
            int r = r0 + rem / XS, col = rem % XS;
            xpad[((size_t)(b * C + half * 8 + j) * XR + r) * XS + col] = 0.f;
        }
    }

    const float4 z4 = make_float4(0.f, 0.f, 0.f, 0.f);
    #pragma unroll
    for (int j = 0; j < 6; ++j) {
        int m = tid + j * 256;
        int ic = m / 96, rem = m - ic * 96, r = rem >> 5, qq = rem & 31;
        int row = h + r - 1;
        float4 v = ((unsigned)row < 128u)
                 ? ld4(in + ((size_t)(b * C + ic) * H + row) * W + qq * 4) : z4;
        *(float4*)&xs[ic][r][qq * 4] = v;
    }
    __syncthreads();

    bool wm = (px > 0), wp = (px < 127);
    float a0 = 0.f, a1 = 0.f, a2 = 0.f, a3 = 0.f;

    #pragma unroll 1
    for (int ic = 0; ic < 16; ++ic) {
        float t[9];
        #pragma unroll
        for (int r = 0; r < 3; ++r) {
            t[r * 3 + 0] = wm ? xs[ic][r][px - 1] : 0.f;
            t[r * 3 + 1] = xs[ic][r][px];
            t[r * 3 + 2] = wp ? xs[ic][r][px + 1] : 0.f;
        }
        #pragma unroll
        for (int j = 0; j < 4; ++j) {
            const float* wp9 = ws + (oc0 + j) * 144 + ic * 9;
            float s = fmaf(wp9[0], t[0], fmaf(wp9[1], t[1], fmaf(wp9[2], t[2],
                      fmaf(wp9[3], t[3], fmaf(wp9[4], t[4], fmaf(wp9[5], t[5],
                      fmaf(wp9[6], t[6], fmaf(wp9[7], t[7], wp9[8] * t[8]))))))));
            if (j == 0) a0 += s; else if (j == 1) a1 += s;
            else if (j == 2) a2 += s; else a3 += s;
        }
    }

    float* xp = xpad + ((size_t)(b * C + oc0) * XR + (h + 9)) * XS + (px + 9);
    float v;
    v = a0 + bs[oc0 + 0]; xp[0]       = 0.5f * v * (1.0f + erff(v * 0.70710678f));
    v = a1 + bs[oc0 + 1]; xp[XCH]     = 0.5f * v * (1.0f + erff(v * 0.70710678f));
    v = a2 + bs[oc0 + 2]; xp[2 * XCH] = 0.5f * v * (1.0f + erff(v * 0.70710678f));
    v = a3 + bs[oc0 + 3]; xp[3 * XCH] = 0.5f * v * (1.0f + erff(v * 0.70710678f));
}

// ===========================================================================
// conv2 (FROZEN r17): LDS row-staged, #pragma unroll 1 on ic.
// ===========================================================================
__global__ __launch_bounds__(256) void conv2_sig(
    const float* __restrict__ ypad, const float* __restrict__ w2,
    const float* __restrict__ b2, float* __restrict__ out)
{
    __shared__ float ws[2304];
    __shared__ float bs[16];
    __shared__ __align__(16) float ys[16][3][136];   // 26.1 KB

    int tid = threadIdx.x;
    for (int i = tid; i < 2304; i += 256) ws[i] = w2[i];
    if (tid < 16) bs[tid] = b2[tid];

    int px  = tid & 127;
    int ocg = tid >> 7;
    int blk = blockIdx.x;                // 512 = half2 x h128 x b2
    int half = blk & 1;
    int h   = (blk >> 1) & 127;
    int b   = blk >> 8;
    int oc0 = half * 8 + ocg * 4;

    #pragma unroll
    for (int j = 0; j < 7; ++j) {
        int m = tid + j * 256;
        if (m < 1632) {
            int ic = m / 102, rem = m - ic * 102, r = rem / 34, qq = rem % 34;
            float4 v = ld4(ypad + ((size_t)(b * C + ic) * YR + (h + r)) * YS + qq * 4);
            *(float4*)&ys[ic][r][qq * 4] = v;
        }
    }
    __syncthreads();

    float a0 = 0.f, a1 = 0.f, a2 = 0.f, a3 = 0.f;

    #pragma unroll 1
    for (int ic = 0; ic < 16; ++ic) {
        float t[9];
        #pragma unroll
        for (int r = 0; r < 3; ++r) {
            t[r * 3 + 0] = ys[ic][r][px + 3];
            t[r * 3 + 1] = ys[ic][r][px + 4];
            t[r * 3 + 2] = ys[ic][r][px + 5];
        }
        #pragma unroll
        for (int j = 0; j < 4; ++j) {
            const float* wp9 = ws + (oc0 + j) * 144 + ic * 9;
            float s = fmaf(wp9[0], t[0], fmaf(wp9[1], t[1], fmaf(wp9[2], t[2],
                      fmaf(wp9[3], t[3], fmaf(wp9[4], t[4], fmaf(wp9[5], t[5],
                      fmaf(wp9[6], t[6], fmaf(wp9[7], t[7], wp9[8] * t[8]))))))));
            if (j == 0) a0 += s; else if (j == 1) a1 += s;
            else if (j == 2) a2 += s; else a3 += s;
        }
    }

    float* op = out + ((size_t)(b * C + oc0) * H + h) * W + px;
    float v;
    v = a0 + bs[oc0 + 0]; op[0]      = 1.0f / (1.0f + expf(-v));
    v = a1 + bs[oc0 + 1]; op[HW]     = 1.0f / (1.0f + expf(-v));
    v = a2 + bs[oc0 + 2]; op[2 * HW] = 1.0f / (1.0f + expf(-v));
    v = a3 + bs[oc0 + 3]; op[3 * HW] = 1.0f / (1.0f + expf(-v));
}

// ---------------------------------------------------------------------------
extern "C" void kernel_launch(void* const* d_in, const int* in_sizes, int n_in,
                              void* d_out, int out_size, void* d_ws, size_t ws_size,
                              hipStream_t stream)
{
    const float* input  = (const float*)d_in[0];
    const float* kernel = (const float*)d_in[1];
    const float* w1     = (const float*)d_in[2];
    const float* b1     = (const float*)d_in[3];
    const float* w2     = (const float*)d_in[4];
    const float* b2     = (const float*)d_in[5];
    float* out = (float*)d_out;

    float* xpad = (float*)d_ws;
    float* ypad = xpad + XPAD_ELEMS;

    conv1_gelu<<<512, 256, 0, stream>>>(input, w1, b1, xpad);
    kpn19<<<512, 1024, 0, stream>>>(xpad, kernel, ypad);
    conv2_sig<<<512, 256, 0, stream>>>(ypad, w2, b2, out);
}

// Round 20
// 53.101 us; speedup vs baseline: 4.9603x; 1.1825x over previous
//
#include <hip/hip_runtime.h>
#include <math.h>

constexpr int B = 2, C = 16, H = 128, W = 128;
constexpr int HW = H * W;

// xpad: [B,16,146,148]; orig (h,w) -> (h+9, w+9); pads zeroed by conv1
constexpr int XR = 146, XS = 148, XCH = XR * XS;
constexpr size_t XPAD_ELEMS = (size_t)B * C * XCH;

// ypad: [B,16,130,136]; orig (h,w) -> (h+1, w+4); pads zeroed by kpn19
constexpr int YR = 130, YS = 136, YCH = YR * YS;

__device__ __forceinline__ float4 ld4(const float* p) { return *(const float4*)p; }

// ===========================================================================
// kpn19 (REVERTED to r16 exact — best measured version):
// q-split + kv[19] VMEM kern batch + LDS x-staging, vmcnt(0)+syncthreads/row.
// ===========================================================================
__global__ __launch_bounds__(1024) void kpn19(
    const float* __restrict__ xpad,  // [B,16,146,148]
    const float* __restrict__ kern,  // [B,361,128,128]
    float* __restrict__ ypad)        // [B,16,130,136]
{
    __shared__ __align__(16) float xls[4][2][16][84];   // 43,008 B
    __shared__ float red[3][16][64];                    // 12,288 B

    int tid  = threadIdx.x;
    int lane = tid & 63;
    int wq   = (tid >> 6) & 3;       // wave within q == channel group
    int q    = tid >> 8;             // kh-quarter, wave-uniform
    int blk  = blockIdx.x;           // 512 = wb2 x h128 x b2
    int wb   = blk & 1;
    int h    = (blk >> 1) & 127;
    int b    = blk >> 8;
    int px   = wb * 64 + lane;
    int c0   = wq * 4;

    // ---- ypad pad zeroing (replaces memset) ----
    if (tid < 64) {
        int pl = tid >> 2, i = tid & 3;
        int col = wb ? 132 + i : i;
        ypad[((size_t)(b * C + pl) * YR + (h + 1)) * YS + col] = 0.f;
    }
    if (h == 0 || h == 127) {
        int r = (h == 0) ? 0 : 129;
        for (int f = tid; f < 1088; f += 1024) {
            int pl = f / 68, col = wb * 68 + f % 68;
            ypad[((size_t)(b * C + pl) * YR + r) * YS + col] = 0.f;
        }
    }

    // ---- x staging sources: q-group covers 336 chunks = [16 ch][21 col4] ----
    int idx = tid & 255;
    int ma  = idx;
    int mb  = idx + 256;
    bool vb = (mb < 336);
    int ca  = ma / 21, cola = ma % 21;
    int cb  = vb ? mb / 21 : 0, colb = vb ? mb % 21 : 0;
    int kh0 = q * 5;
    int nkh = (q == 3) ? 4 : 5;

    const float* sa = xpad + (size_t)(b * C + ca) * XCH
                      + (size_t)(h + kh0) * XS + wb * 64 + cola * 4;
    const float* sb = xpad + (size_t)(b * C + cb) * XCH
                      + (size_t)(h + kh0) * XS + wb * 64 + colb * 4;

    const float* kp = kern + (size_t)b * 361 * HW + (size_t)h * W + px;

    float a0 = 0.f, a1 = 0.f, a2 = 0.f, a3 = 0.f;

#define STAGE(bufsel)                                                         \
    {                                                                         \
        __builtin_amdgcn_global_load_lds((const void*)sa,                     \
            (void*)(&xls[q][bufsel][0][0] + wq * 256), 16, 0, 0);             \
        if (vb)                                                               \
            __builtin_amdgcn_global_load_lds((const void*)sb,                 \
                (void*)(&xls[q][bufsel][0][0] + 1024 + wq * 256), 16, 0, 0);  \
        sa += XS; sb += XS;                                                   \
    }

    STAGE(0);
    asm volatile("s_waitcnt vmcnt(0)" ::: "memory");
    __syncthreads();

    #pragma unroll
    for (int r = 0; r < 5; ++r) {
        const int cur = r & 1;
        if (r + 1 < nkh) STAGE(cur ^ 1);
        if (r < nkh) {
            int kh = kh0 + r;
            float kv[19];
            const float* kpr = kp + (size_t)(kh * 19) * HW;
            #pragma unroll
            for (int kw = 0; kw < 19; ++kw)
                kv[kw] = kpr[(size_t)kw * HW];
            __builtin_amdgcn_sched_barrier(0);
            #pragma unroll
            for (int kw = 0; kw < 19; ++kw) {
                float k = kv[kw];
                a0 = fmaf(xls[q][cur][c0 + 0][lane + kw], k, a0);
                a1 = fmaf(xls[q][cur][c0 + 1][lane + kw], k, a1);
                a2 = fmaf(xls[q][cur][c0 + 2][lane + kw], k, a2);
                a3 = fmaf(xls[q][cur][c0 + 3][lane + kw], k, a3);
            }
        }
        asm volatile("s_waitcnt vmcnt(0)" ::: "memory");
        __syncthreads();
    }
#undef STAGE

    if (q > 0) {
        red[q - 1][c0 + 0][lane] = a0;
        red[q - 1][c0 + 1][lane] = a1;
        red[q - 1][c0 + 2][lane] = a2;
        red[q - 1][c0 + 3][lane] = a3;
    }
    __syncthreads();
    if (q == 0) {
        #pragma unroll
        for (int j = 0; j < 3; ++j) {
            a0 += red[j][c0 + 0][lane];
            a1 += red[j][c0 + 1][lane];
            a2 += red[j][c0 + 2][lane];
            a3 += red[j][c0 + 3][lane];
        }
        float* yp = ypad + ((size_t)(b * C + c0) * YR + (h + 1)) * YS + (px + 4);
        yp[0]       = a0;
        yp[YCH]     = a1;
        yp[2 * YCH] = a2;
        yp[3 * YCH] = a3;
    }
}

// ===========================================================================
// conv1: 3x3 conv (pad 1) + exact GELU -> xpad. ONE block per (h,b):
// grid = h128 x b2 = 256 blocks, block = 512 thr = 128 px x 4 ocg.
// Staging tile loaded ONCE (was duplicated across 2 half-blocks in r17).
// Per-ic ds_read batch + 36 FMA, #pragma unroll 1 (spill-free regime).
// ===========================================================================
__global__ __launch_bounds__(512) void conv1_gelu(
    const float* __restrict__ in, const float* __restrict__ w1,
    const float* __restrict__ b1, float* __restrict__ xpad)
{
    __shared__ float ws[2304];
    __shared__ float bs[16];
    __shared__ __align__(16) float xs[16][3][128];   // 24 KB

    int tid = threadIdx.x;
    for (int i = tid; i < 2304; i += 512) ws[i] = w1[i];
    if (tid < 16) bs[tid] = b1[tid];

    int px  = tid & 127;
    int ocg = tid >> 7;                  // 0..3, wave-uniform
    int blk = blockIdx.x;                // 256 = h128 x b2
    int h   = blk & 127;
    int b   = blk >> 7;
    int oc0 = ocg * 4;

    // ---- xpad pad zeroing for ALL 16 planes of this (h,b) ----
    if (tid < 320) {
        int j = tid / 20, i = tid % 20;
        int col = (i < 9) ? i : 128 + i;             // 0..8, 137..147
        xpad[((size_t)(b * C + j) * XR + (h + 9)) * XS + col] = 0.f;
    }
    if (h == 0 || h == 127) {
        int r0 = (h == 0) ? 0 : 137;
        for (int f = tid; f < 16 * 9 * XS; f += 512) {
            int j = f / (9 * XS), rem = f % (9 * XS);
            int r = r0 + rem / XS, col = rem % XS;
            xpad[((size_t)(b * C + j) * XR + r) * XS + col] = 0.f;
        }
    }

    // ---- stage rows h-1..h+1 x 16 ic into LDS (coalesced float4, once) ----
    const float4 z4 = make_float4(0.f, 0.f, 0.f, 0.f);
    #pragma unroll
    for (int j = 0; j < 3; ++j) {
        int m = tid + j * 512;           // < 1536 exactly
        int ic = m / 96, rem = m - ic * 96, r = rem >> 5, qq = rem & 31;
        int row = h + r - 1;
        float4 v = ((unsigned)row < 128u)
                 ? ld4(in + ((size_t)(b * C + ic) * H + row) * W + qq * 4) : z4;
        *(float4*)&xs[ic][r][qq * 4] = v;
    }
    __syncthreads();

    bool wm = (px > 0), wp = (px < 127);
    float a0 = 0.f, a1 = 0.f, a2 = 0.f, a3 = 0.f;

    #pragma unroll 1
    for (int ic = 0; ic < 16; ++ic) {
        float t[9];
        #pragma unroll
        for (int r = 0; r < 3; ++r) {
            t[r * 3 + 0] = wm ? xs[ic][r][px - 1] : 0.f;
            t[r * 3 + 1] = xs[ic][r][px];
            t[r * 3 + 2] = wp ? xs[ic][r][px + 1] : 0.f;
        }
        #pragma unroll
        for (int j = 0; j < 4; ++j) {
            const float* wp9 = ws + (oc0 + j) * 144 + ic * 9;
            float s = fmaf(wp9[0], t[0], fmaf(wp9[1], t[1], fmaf(wp9[2], t[2],
                      fmaf(wp9[3], t[3], fmaf(wp9[4], t[4], fmaf(wp9[5], t[5],
                      fmaf(wp9[6], t[6], fmaf(wp9[7], t[7], wp9[8] * t[8]))))))));
            if (j == 0) a0 += s; else if (j == 1) a1 += s;
            else if (j == 2) a2 += s; else a3 += s;
        }
    }

    float* xp = xpad + ((size_t)(b * C + oc0) * XR + (h + 9)) * XS + (px + 9);
    float v;
    v = a0 + bs[oc0 + 0]; xp[0]       = 0.5f * v * (1.0f + erff(v * 0.70710678f));
    v = a1 + bs[oc0 + 1]; xp[XCH]     = 0.5f * v * (1.0f + erff(v * 0.70710678f));
    v = a2 + bs[oc0 + 2]; xp[2 * XCH] = 0.5f * v * (1.0f + erff(v * 0.70710678f));
    v = a3 + bs[oc0 + 3]; xp[3 * XCH] = 0.5f * v * (1.0f + erff(v * 0.70710678f));
}

// ===========================================================================
// conv2: 3x3 conv (pad 1) + sigmoid -> out. Same one-block-per-(h,b) change.
// ===========================================================================
__global__ __launch_bounds__(512) void conv2_sig(
    const float* __restrict__ ypad, const float* __restrict__ w2,
    const float* __restrict__ b2, float* __restrict__ out)
{
    __shared__ float ws[2304];
    __shared__ float bs[16];
    __shared__ __align__(16) float ys[16][3][136];   // 26.1 KB

    int tid = threadIdx.x;
    for (int i = tid; i < 2304; i += 512) ws[i] = w2[i];
    if (tid < 16) bs[tid] = b2[tid];

    int px  = tid & 127;
    int ocg = tid >> 7;
    int blk = blockIdx.x;                // 256 = h128 x b2
    int h   = blk & 127;
    int b   = blk >> 7;
    int oc0 = ocg * 4;

    // stage padded rows h..h+2 x 16 ic, cols 0..135 (once)
    #pragma unroll
    for (int j = 0; j < 4; ++j) {
        int m = tid + j * 512;
        if (m < 1632) {
            int ic = m / 102, rem = m - ic * 102, r = rem / 34, qq = rem % 34;
            float4 v = ld4(ypad + ((size_t)(b * C + ic) * YR + (h + r)) * YS + qq * 4);
            *(float4*)&ys[ic][r][qq * 4] = v;
        }
    }
    __syncthreads();

    float a0 = 0.f, a1 = 0.f, a2 = 0.f, a3 = 0.f;

    #pragma unroll 1
    for (int ic = 0; ic < 16; ++ic) {
        float t[9];
        #pragma unroll
        for (int r = 0; r < 3; ++r) {
            t[r * 3 + 0] = ys[ic][r][px + 3];
            t[r * 3 + 1] = ys[ic][r][px + 4];
            t[r * 3 + 2] = ys[ic][r][px + 5];
        }
        #pragma unroll
        for (int j = 0; j < 4; ++j) {
            const float* wp9 = ws + (oc0 + j) * 144 + ic * 9;
            float s = fmaf(wp9[0], t[0], fmaf(wp9[1], t[1], fmaf(wp9[2], t[2],
                      fmaf(wp9[3], t[3], fmaf(wp9[4], t[4], fmaf(wp9[5], t[5],
                      fmaf(wp9[6], t[6], fmaf(wp9[7], t[7], wp9[8] * t[8]))))))));
            if (j == 0) a0 += s; else if (j == 1) a1 += s;
            else if (j == 2) a2 += s; else a3 += s;
        }
    }

    float* op = out + ((size_t)(b * C + oc0) * H + h) * W + px;
    float v;
    v = a0 + bs[oc0 + 0]; op[0]      = 1.0f / (1.0f + expf(-v));
    v = a1 + bs[oc0 + 1]; op[HW]     = 1.0f / (1.0f + expf(-v));
    v = a2 + bs[oc0 + 2]; op[2 * HW] = 1.0f / (1.0f + expf(-v));
    v = a3 + bs[oc0 + 3]; op[3 * HW] = 1.0f / (1.0f + expf(-v));
}

// ---------------------------------------------------------------------------
extern "C" void kernel_launch(void* const* d_in, const int* in_sizes, int n_in,
                              void* d_out, int out_size, void* d_ws, size_t ws_size,
                              hipStream_t stream)
{
    const float* input  = (const float*)d_in[0];
    const float* kernel = (const float*)d_in[1];
    const float* w1     = (const float*)d_in[2];
    const float* b1     = (const float*)d_in[3];
    const float* w2     = (const float*)d_in[4];
    const float* b2     = (const float*)d_in[5];
    float* out = (float*)d_out;

    float* xpad = (float*)d_ws;
    float* ypad = xpad + XPAD_ELEMS;

    conv1_gelu<<<256, 512, 0, stream>>>(input, w1, b1, xpad);
    kpn19<<<512, 1024, 0, stream>>>(xpad, kernel, ypad);
    conv2_sig<<<256, 512, 0, stream>>>(ypad, w2, b2, out);
}